// Round 7
// baseline (890.611 us; speedup 1.0000x reference)
//
#include <hip/hip_runtime.h>
#include <math.h>

#define NN 50000
#define NE 800000
#define NG 128
#define DIM 128
#define CLASSES 10

// ---------------- utility ----------------

__global__ void zero_kernel(float* __restrict__ p, int n4) {
    int i = blockIdx.x * blockDim.x + threadIdx.x;
    int stride = gridDim.x * blockDim.x;
    float4 z = make_float4(0.f, 0.f, 0.f, 0.f);
    for (; i < n4; i += stride) ((float4*)p)[i] = z;
}

__global__ void zero_int_kernel(int* __restrict__ p, int n) {
    int i = blockIdx.x * blockDim.x + threadIdx.x;
    int stride = gridDim.x * blockDim.x;
    for (; i < n; i += stride) p[i] = 0;
}

// ---------------- CSR build ----------------

__global__ void count_kernel(const int* __restrict__ dst, int* __restrict__ cnt, int E) {
    int i = blockIdx.x * blockDim.x + threadIdx.x;
    int stride = gridDim.x * blockDim.x;
    for (; i < E; i += stride) atomicAdd(&cnt[dst[i]], 1);
}

__global__ void norm_from_cnt_kernel(const int* __restrict__ cnt, float* __restrict__ nrm, int n) {
    int i = blockIdx.x * blockDim.x + threadIdx.x;
    if (i < n) {
        float v = (float)cnt[i];
        v = v < 1.f ? 1.f : v;
        nrm[i] = 1.0f / sqrtf(v);
    }
}

// single-block exclusive scan via wave shuffles
__global__ __launch_bounds__(1024) void scan_kernel(const int* __restrict__ cnt,
                                                    int* __restrict__ rowptr, int n) {
    __shared__ int wsum[16];
    __shared__ int base;
    int t = threadIdx.x;
    int lane = t & 63, wv = t >> 6;
    if (t == 0) { base = 0; rowptr[0] = 0; }
    __syncthreads();
    for (int start = 0; start < n; start += 1024) {
        int i = start + t;
        int v = (i < n) ? cnt[i] : 0;
#pragma unroll
        for (int off = 1; off < 64; off <<= 1) {
            int u = __shfl_up(v, off);
            if (lane >= off) v += u;
        }
        if (lane == 63) wsum[wv] = v;
        __syncthreads();
        if (wv == 0) {
            int s = (lane < 16) ? wsum[lane] : 0;
#pragma unroll
            for (int off = 1; off < 16; off <<= 1) {
                int u = __shfl_up(s, off);
                if (lane >= off) s += u;
            }
            if (lane < 16) wsum[lane] = s;
        }
        __syncthreads();
        int woff = (wv > 0) ? wsum[wv - 1] : 0;
        if (i < n) rowptr[i + 1] = base + woff + v;
        __syncthreads();
        if (t == 0) base += wsum[15];
        __syncthreads();
    }
}

__global__ void copy_int_kernel(const int* __restrict__ a, int* __restrict__ b, int n) {
    int i = blockIdx.x * blockDim.x + threadIdx.x;
    int stride = gridDim.x * blockDim.x;
    for (; i < n; i += stride) b[i] = a[i];
}

__global__ void fill_kernel(const int* __restrict__ src, const int* __restrict__ dst,
                            int* __restrict__ rowcur, int* __restrict__ esrc, int E) {
    int i = blockIdx.x * blockDim.x + threadIdx.x;
    int stride = gridDim.x * blockDim.x;
    for (; i < E; i += stride) {
        int pos = atomicAdd(&rowcur[dst[i]], 1);
        esrc[pos] = src[i];
    }
}

// ---------------- propagation hop ----------------
// out[i] = nrm[i] * sum_{e: dst=i} feat[src]*nrm[src]
// One wave per node. Each HALF-wave gathers one full 512B row as float4
// (2 edges per load instr); one bpermute each for s and w per edge-pair
// (lane-dependent selector). Cross-half combine via 4 shfl_xor at the end.

__global__ __launch_bounds__(256) void gather_hop_kernel(
    const float* __restrict__ feat, const float* __restrict__ nrm,
    const int* __restrict__ rowptr, const int* __restrict__ esrc,
    float* __restrict__ out, int n) {
    int wid = (blockIdx.x * blockDim.x + threadIdx.x) >> 6;
    int lane = threadIdx.x & 63;
    if (wid >= n) return;
    int beg = rowptr[wid], end = rowptr[wid + 1];
    int deg = end - beg;
    int half = lane >> 5;   // which edge of the pair this half-wave handles
    int l32 = lane & 31;    // float4 slot within the 512B row
    float4 acc = make_float4(0.f, 0.f, 0.f, 0.f);
    for (int b = 0; b < deg; b += 64) {
        int rem = deg - b; if (rem > 64) rem = 64;
        int sE = 0; float wE = 0.f;   // lanes >= rem keep (0, 0) -> phantom edges are no-ops
        if (lane < rem) {
            sE = esrc[beg + b + lane];
            wE = nrm[sE];
        }
        int k = 0;
        for (; k + 7 < rem; k += 8) {
#pragma unroll
            for (int u = 0; u < 4; ++u) {
                int sel = k + 2 * u + half;
                int s = __shfl(sE, sel);
                float w = __shfl(wE, sel);
                float4 v = ((const float4*)(feat + (size_t)s * DIM))[l32];
                acc.x += v.x * w; acc.y += v.y * w;
                acc.z += v.z * w; acc.w += v.w * w;
            }
        }
        for (; k < rem; k += 2) {
            int sel = k + half;           // may point at a phantom edge: w=0 there
            int s = __shfl(sE, sel);
            float w = __shfl(wE, sel);
            float4 v = ((const float4*)(feat + (size_t)s * DIM))[l32];
            acc.x += v.x * w; acc.y += v.y * w;
            acc.z += v.z * w; acc.w += v.w * w;
        }
    }
    // combine the two half-wave partials (same dims, different edge subsets)
    acc.x += __shfl_xor(acc.x, 32);
    acc.y += __shfl_xor(acc.y, 32);
    acc.z += __shfl_xor(acc.z, 32);
    acc.w += __shfl_xor(acc.w, 32);
    float nd = nrm[wid];
    if (lane < 32) {
        ((float4*)(out + (size_t)wid * DIM))[l32] =
            make_float4(acc.x * nd, acc.y * nd, acc.z * nd, acc.w * nd);
    }
}

// ---------------- fp32 GEMM: out[M,128] = relu([A0|A1|A2] @ W + b) ----------------
// 128x128 tile, 256 threads, per-thread 8x8 as rows {r0..r0+3, r0+64..r0+67} x
// cols {c0..c0+3, c0+64..c0+67} (conflict-free LDS reads). Register prefetch of
// the next K-chunk overlaps global latency with the 2048-FMA compute phase.
// In-place (out aliases A0) is safe: each block reads only its own 128 rows.

#define BM 128
#define BK 32

__global__ __launch_bounds__(256) void gemm_kernel(
    const float* __restrict__ A0, const float* __restrict__ A1, const float* __restrict__ A2,
    const float* __restrict__ W, const float* __restrict__ bias,
    float* __restrict__ out, int M) {
    __shared__ float As[BK][BM + 4];   // transposed A tile
    __shared__ float Wt[BK][DIM];

    int tid = threadIdx.x;
    int row0 = blockIdx.x * BM;
    int r0 = (tid >> 4) * 4;   // row group: {r0..r0+3} and {r0+64..}
    int c0 = (tid & 15) * 4;   // col group: {c0..c0+3} and {c0+64..}

    // staging coords
    int ar = tid >> 3;         // A row within tile (+32*it)
    int ak = (tid & 7) * 4;    // A k4
    int wk = tid >> 5;         // W k within chunk (+8*it)
    int wc = (tid & 31) * 4;   // W col

    const float* parts[3] = {A0, A1, A2};

    float4 pa[4], pw[4];
    // preload chunk 0 (p=0, kc=0)
#pragma unroll
    for (int it = 0; it < 4; ++it) {
        int grow = row0 + ar + 32 * it;
        pa[it] = (grow < M) ? *(const float4*)(A0 + (size_t)grow * DIM + ak)
                            : make_float4(0.f, 0.f, 0.f, 0.f);
        pw[it] = *(const float4*)(W + (size_t)(wk + 8 * it) * DIM + wc);
    }

    float acc[8][8];
#pragma unroll
    for (int i = 0; i < 8; i++)
#pragma unroll
        for (int j = 0; j < 8; j++) acc[i][j] = 0.f;

    for (int t = 0; t < 12; ++t) {
        __syncthreads();
        // regs -> LDS
#pragma unroll
        for (int it = 0; it < 4; ++it) {
            int r = ar + 32 * it;
            As[ak + 0][r] = pa[it].x;
            As[ak + 1][r] = pa[it].y;
            As[ak + 2][r] = pa[it].z;
            As[ak + 3][r] = pa[it].w;
            *(float4*)(&Wt[wk + 8 * it][wc]) = pw[it];
        }
        __syncthreads();
        // issue next chunk's loads; latency hides under the FMA block below
        if (t < 11) {
            int tn = t + 1;
            const float* A = parts[tn >> 2];
            int kc = (tn & 3) * BK;
#pragma unroll
            for (int it = 0; it < 4; ++it) {
                int grow = row0 + ar + 32 * it;
                pa[it] = (grow < M) ? *(const float4*)(A + (size_t)grow * DIM + kc + ak)
                                    : make_float4(0.f, 0.f, 0.f, 0.f);
                pw[it] = *(const float4*)(W + (size_t)((tn >> 2) * DIM + kc + wk + 8 * it) * DIM + wc);
            }
        }
#pragma unroll
        for (int kk = 0; kk < BK; ++kk) {
            float4 a0 = *(const float4*)(&As[kk][r0]);
            float4 a1 = *(const float4*)(&As[kk][r0 + 64]);
            float4 w0 = *(const float4*)(&Wt[kk][c0]);
            float4 w1 = *(const float4*)(&Wt[kk][c0 + 64]);
            float a[8] = {a0.x, a0.y, a0.z, a0.w, a1.x, a1.y, a1.z, a1.w};
            float w[8] = {w0.x, w0.y, w0.z, w0.w, w1.x, w1.y, w1.z, w1.w};
#pragma unroll
            for (int i = 0; i < 8; i++)
#pragma unroll
                for (int j = 0; j < 8; j++) acc[i][j] += a[i] * w[j];
        }
    }

    // epilogue: bias + relu + float4 stores
#pragma unroll
    for (int i = 0; i < 8; i++) {
        int grow = row0 + (i < 4 ? r0 + i : 64 + r0 + i - 4);
        if (grow < M) {
            float4 o0, o1;
            o0.x = acc[i][0] + bias[c0 + 0]; o0.y = acc[i][1] + bias[c0 + 1];
            o0.z = acc[i][2] + bias[c0 + 2]; o0.w = acc[i][3] + bias[c0 + 3];
            o1.x = acc[i][4] + bias[c0 + 64 + 0]; o1.y = acc[i][5] + bias[c0 + 64 + 1];
            o1.z = acc[i][6] + bias[c0 + 64 + 2]; o1.w = acc[i][7] + bias[c0 + 64 + 3];
            o0.x = o0.x > 0.f ? o0.x : 0.f; o0.y = o0.y > 0.f ? o0.y : 0.f;
            o0.z = o0.z > 0.f ? o0.z : 0.f; o0.w = o0.w > 0.f ? o0.w : 0.f;
            o1.x = o1.x > 0.f ? o1.x : 0.f; o1.y = o1.y > 0.f ? o1.y : 0.f;
            o1.z = o1.z > 0.f ? o1.z : 0.f; o1.w = o1.w > 0.f ? o1.w : 0.f;
            *(float4*)(out + (size_t)grow * DIM + c0) = o0;
            *(float4*)(out + (size_t)grow * DIM + c0 + 64) = o1;
        }
    }
}

// ---------------- pooling + head ----------------

#define PCHUNK 64

__global__ __launch_bounds__(128) void pool_partial_kernel(
    const float* __restrict__ h, const int* __restrict__ gid,
    float* __restrict__ gsum, int n) {
    int d = threadIdx.x;
    int i0 = blockIdx.x * PCHUNK;
    if (i0 >= n) return;
    int i1 = i0 + PCHUNK; if (i1 > n) i1 = n;
    int curg = gid[i0];
    float acc = 0.f;
    for (int i = i0; i < i1; ++i) {
        int g = gid[i];
        if (g != curg) {
            atomicAdd(&gsum[(size_t)curg * DIM + d], acc);
            acc = 0.f;
            curg = g;
        }
        acc += h[(size_t)i * DIM + d];
    }
    atomicAdd(&gsum[(size_t)curg * DIM + d], acc);
}

__global__ __launch_bounds__(128) void head_kernel(
    const float* __restrict__ gsum, const int* __restrict__ gid,
    const float* __restrict__ Wc, const float* __restrict__ bc,
    float* __restrict__ out) {
    __shared__ float v[DIM];
    __shared__ int sbeg, send;
    int g = blockIdx.x;
    int t = threadIdx.x;
    if (t == 0) {
        int lo = 0, hi = NN;
        while (lo < hi) { int m = (lo + hi) >> 1; if (gid[m] < g) lo = m + 1; else hi = m; }
        sbeg = lo;
    }
    if (t == 1) {
        int lo = 0, hi = NN;
        while (lo < hi) { int m = (lo + hi) >> 1; if (gid[m] < g + 1) lo = m + 1; else hi = m; }
        send = lo;
    }
    __syncthreads();
    float c = (float)(send - sbeg);
    c = c < 1.f ? 1.f : c;
    v[t] = gsum[(size_t)g * DIM + t] / c;
    __syncthreads();
    if (t < CLASSES) {
        float o = bc[t];
#pragma unroll 16
        for (int d = 0; d < DIM; ++d) o += v[d] * Wc[d * CLASSES + t];
        out[g * CLASSES + t] = o;
    }
}

// ---------------- launch ----------------

extern "C" void kernel_launch(void* const* d_in, const int* in_sizes, int n_in,
                              void* d_out, int out_size, void* d_ws, size_t ws_size,
                              hipStream_t stream) {
    const float* x   = (const float*)d_in[0];
    const int*   src = (const int*)d_in[1];
    const int*   dst = (const int*)d_in[2];
    const int*   gid = (const int*)d_in[3];
    const float* W0  = (const float*)d_in[4];
    const float* b0  = (const float*)d_in[5];
    const float* W1  = (const float*)d_in[6];
    const float* b1  = (const float*)d_in[7];
    const float* W2  = (const float*)d_in[8];
    const float* b2  = (const float*)d_in[9];
    const float* Wc  = (const float*)d_in[10];
    const float* bc  = (const float*)d_in[11];
    float* out = (float*)d_out;

    // workspace: floats nrm[N] | h[N*D] | f1[N*D] | f2[N*D] | gsum[G*D]
    //            ints   cnt[N] | rowptr[N+1] | esrc[E]
    float* nrm  = (float*)d_ws;
    float* h    = nrm + NN;
    float* f1   = h + (size_t)NN * DIM;
    float* f2   = f1 + (size_t)NN * DIM;
    float* gsum = f2 + (size_t)NN * DIM;
    int* cnt    = (int*)(gsum + (size_t)NG * DIM);
    int* rowptr = cnt + NN;
    int* esrc   = rowptr + NN + 1;

    // CSR build (amortized over 6 hops)
    zero_int_kernel<<<64, 256, 0, stream>>>(cnt, NN);
    count_kernel<<<1024, 256, 0, stream>>>(dst, cnt, NE);
    norm_from_cnt_kernel<<<(NN + 255) / 256, 256, 0, stream>>>(cnt, nrm, NN);
    scan_kernel<<<1, 1024, 0, stream>>>(cnt, rowptr, NN);
    copy_int_kernel<<<64, 256, 0, stream>>>(rowptr, cnt, NN);  // cnt becomes rowcur
    fill_kernel<<<1024, 256, 0, stream>>>(src, dst, cnt, esrc, NE);

    const float* Ws_[3] = {W0, W1, W2};
    const float* bs_[3] = {b0, b1, b2};
    const float* featIn = x;
    const int hop_blocks = (NN * 64 + 255) / 256;
    for (int l = 0; l < 3; ++l) {
        gather_hop_kernel<<<hop_blocks, 256, 0, stream>>>(featIn, nrm, rowptr, esrc, f1, NN);
        gather_hop_kernel<<<hop_blocks, 256, 0, stream>>>(f1, nrm, rowptr, esrc, f2, NN);
        gemm_kernel<<<(NN + BM - 1) / BM, 256, 0, stream>>>(featIn, f1, f2, Ws_[l], bs_[l], h, NN);
        featIn = h;
    }

    // pooling + head
    zero_kernel<<<16, 256, 0, stream>>>(gsum, NG * DIM / 4);
    pool_partial_kernel<<<(NN + PCHUNK - 1) / PCHUNK, 128, 0, stream>>>(h, gid, gsum, NN);
    head_kernel<<<NG, DIM, 0, stream>>>(gsum, gid, Wc, bc, out);
}